// Round 1
// baseline (383.211 us; speedup 1.0000x reference)
//
#include <hip/hip_runtime.h>

// Problem constants (from reference: shape (2, 1, 160, 192, 160), win=9)
#define BB 2
#define DD 160
#define HH 192
#define WW 160
#define HW (HH * WW)          // 30720
#define PAD 4
#define WIN_SIZE 729.0f
#define EPS 1e-5f

// ---------------------------------------------------------------------------
// Pass 1: W-filter. Reads x,y, computes the 5 quantities (x, y, x^2, y^2, xy)
// and box-sums them along W (zero-padded). Output T: 5 channels, each
// [nSlices][H][W], channel stride tq.
// ---------------------------------------------------------------------------
__global__ void __launch_bounds__(256) k_wfilter(
    const float* __restrict__ x, const float* __restrict__ y,
    float* __restrict__ T, long tq, int b, int d0ext, int nSlices)
{
    int idx = blockIdx.x * 256 + threadIdx.x;
    int total = nSlices * HW;
    if (idx >= total) return;
    int w = idx % WW;
    int h = (idx / WW) % HH;
    int s = idx / HW;

    long rowoff = (((long)b * DD + (long)(d0ext + s)) * HH + h) * (long)WW;
    const float* xr = x + rowoff;
    const float* yr = y + rowoff;

    int lo = (w - PAD < 0) ? 0 : (w - PAD);
    int hi = (w + PAD >= WW) ? (WW - 1) : (w + PAD);

    float sx = 0.f, sy = 0.f, sxx = 0.f, syy = 0.f, sxy = 0.f;
    for (int u = lo; u <= hi; ++u) {
        float xv = xr[u], yv = yr[u];
        sx += xv;
        sy += yv;
        sxx = fmaf(xv, xv, sxx);
        syy = fmaf(yv, yv, syy);
        sxy = fmaf(xv, yv, sxy);
    }
    long o = (long)s * HW + (long)h * WW + w;
    T[o]          = sx;
    T[o + tq]     = sy;
    T[o + 2 * tq] = sxx;
    T[o + 3 * tq] = syy;
    T[o + 4 * tq] = sxy;
}

// ---------------------------------------------------------------------------
// Pass 2: H-filter. T -> S, 5 channels, box-sum along H (zero-padded).
// ---------------------------------------------------------------------------
__global__ void __launch_bounds__(256) k_hfilter(
    const float* __restrict__ T, float* __restrict__ S, long tq, int nSlices)
{
    int idx = blockIdx.x * 256 + threadIdx.x;
    int total = nSlices * HW;
    if (idx >= total) return;
    int w = idx % WW;
    int h = (idx / WW) % HH;
    int s = idx / HW;

    int lo = (h - PAD < 0) ? 0 : (h - PAD);
    int hi = (h + PAD >= HH) ? (HH - 1) : (h + PAD);

    float a0 = 0.f, a1 = 0.f, a2 = 0.f, a3 = 0.f, a4 = 0.f;
    long base = (long)s * HW + w;
    for (int u = lo; u <= hi; ++u) {
        long o = base + (long)u * WW;
        a0 += T[o];
        a1 += T[o + tq];
        a2 += T[o + 2 * tq];
        a3 += T[o + 3 * tq];
        a4 += T[o + 4 * tq];
    }
    long o = (long)s * HW + (long)h * WW + w;
    S[o]          = a0;
    S[o + tq]     = a1;
    S[o + 2 * tq] = a2;
    S[o + 3 * tq] = a3;
    S[o + 4 * tq] = a4;
}

// ---------------------------------------------------------------------------
// Pass 3: D-filter + cc + per-block reduction.
// S slices are global d in [d0ext, d0ext+nSlices). Outputs for d in
// [d0, d0+nOut). Each block writes one partial sum.
// ---------------------------------------------------------------------------
__global__ void __launch_bounds__(256) k_dfilter_cc(
    const float* __restrict__ S, long tq, int d0, int nOut, int d0ext,
    float* __restrict__ partials, int pbase)
{
    int idx = blockIdx.x * 256 + threadIdx.x;
    int total = nOut * HW;
    float cc = 0.f;
    if (idx < total) {
        int w = idx % WW;
        int h = (idx / WW) % HH;
        int dl = idx / HW;
        int dout = d0 + dl;

        int glo = (dout - PAD < 0) ? 0 : (dout - PAD);
        int ghi = (dout + PAD >= DD) ? (DD - 1) : (dout + PAD);

        float sx = 0.f, sy = 0.f, sxx = 0.f, syy = 0.f, sxy = 0.f;
        long colbase = (long)h * WW + w;
        for (int g = glo; g <= ghi; ++g) {
            long o = (long)(g - d0ext) * HW + colbase;
            sx  += S[o];
            sy  += S[o + tq];
            sxx += S[o + 2 * tq];
            syy += S[o + 3 * tq];
            sxy += S[o + 4 * tq];
        }
        const float inv = 1.0f / WIN_SIZE;
        float cross = sxy - sx * sy * inv;
        float xv = sxx - sx * sx * inv;
        xv = (xv < EPS) ? EPS : xv;
        float yv = syy - sy * sy * inv;
        yv = (yv < EPS) ? EPS : yv;
        cc = (cross * cross) / (xv * yv);
    }

    __shared__ float red[256];
    red[threadIdx.x] = cc;
    __syncthreads();
    for (int off = 128; off > 0; off >>= 1) {
        if (threadIdx.x < off) red[threadIdx.x] += red[threadIdx.x + off];
        __syncthreads();
    }
    if (threadIdx.x == 0) partials[pbase + blockIdx.x] = red[0];
}

// ---------------------------------------------------------------------------
// Pass 4: final reduce of partials -> -mean(cc)
// ---------------------------------------------------------------------------
__global__ void __launch_bounds__(256) k_finalize(
    const float* __restrict__ partials, int n, float* __restrict__ out)
{
    __shared__ double red[256];
    double s = 0.0;
    for (int i = threadIdx.x; i < n; i += 256) s += (double)partials[i];
    red[threadIdx.x] = s;
    __syncthreads();
    for (int off = 128; off > 0; off >>= 1) {
        if (threadIdx.x < off) red[threadIdx.x] += red[threadIdx.x + off];
        __syncthreads();
    }
    if (threadIdx.x == 0) {
        const double Nvox = (double)BB * DD * HH * WW;
        out[0] = (float)(-red[0] / Nvox);
    }
}

extern "C" void kernel_launch(void* const* d_in, const int* in_sizes, int n_in,
                              void* d_out, int out_size, void* d_ws, size_t ws_size,
                              hipStream_t stream) {
    const float* x = (const float*)d_in[0];
    const float* y = (const float*)d_in[1];
    float* out = (float*)d_out;
    float* wsf = (float*)d_ws;

    // Slab sizing: need two 5-channel buffers of capSlices*H*W floats each,
    // plus ~1MB reserve for partial sums.
    const size_t reserve = 1u << 20;
    const size_t perSliceBytes = 5ul * HW * sizeof(float); // both buffers: 2x this
    long maxCap = 1;
    if (ws_size > reserve)
        maxCap = (long)((ws_size - reserve) / (2ul * perSliceBytes));

    int capSlices, slabD;
    if (maxCap >= DD) {
        capSlices = DD;
        slabD = DD;
    } else {
        capSlices = (int)maxCap;
        slabD = capSlices - 2 * PAD;
        if (slabD < 1) { slabD = 1; capSlices = 1 + 2 * PAD; }
    }

    long tq = (long)capSlices * HW;
    float* T        = wsf;
    float* Sbuf     = wsf + 5 * tq;
    float* partials = wsf + 10 * tq;

    int pbase = 0;
    for (int b = 0; b < BB; ++b) {
        for (int d0 = 0; d0 < DD; d0 += slabD) {
            int nOut = (DD - d0 < slabD) ? (DD - d0) : slabD;
            int d0e = (d0 - PAD < 0) ? 0 : (d0 - PAD);
            int d1e = (d0 + nOut + PAD > DD) ? DD : (d0 + nOut + PAD);
            int nS = d1e - d0e;

            int totalF = nS * HW;
            int gridF = (totalF + 255) / 256;
            k_wfilter<<<gridF, 256, 0, stream>>>(x, y, T, tq, b, d0e, nS);
            k_hfilter<<<gridF, 256, 0, stream>>>(T, Sbuf, tq, nS);

            int totalO = nOut * HW;
            int gridO = (totalO + 255) / 256;
            k_dfilter_cc<<<gridO, 256, 0, stream>>>(Sbuf, tq, d0, nOut, d0e,
                                                    partials, pbase);
            pbase += gridO;
        }
    }
    k_finalize<<<1, 256, 0, stream>>>(partials, pbase, out);
}

// Round 2
// 126.041 us; speedup vs baseline: 3.0404x; 3.0404x over previous
//
#include <hip/hip_runtime.h>

// Problem constants (reference: shape (2,1,160,192,160), win=9)
#define BB 2
#define DD 160
#define HH 192
#define WW 160
#define HW (HH * WW)
#define PAD 4
#define WIN 9
#define TH 16
#define TW 16
#define EXT 24            // TH+2*PAD == TW+2*PAD
#define XS_STR 25         // padded row stride for xs/ys
#define WS_STR 17         // padded row stride for wsum/hsum
#define CHUNK 40
#define NCHUNK 4          // DD / CHUNK
#define WT (WW / TW)      // 10
#define HT (HH / TH)      // 12
#define NBLK (WT * HT * NCHUNK * BB)  // 960
#define EPS 1e-5f
#define INV_WS (1.0f / 729.0f)

// ---------------------------------------------------------------------------
// Fused LNCC: W-filter + H-filter in LDS per ext slice, D-filter via per-thread
// 9-deep shift-register running sums, cc + block reduction at the end.
// One block = 16x16 (H,W) output tile x 40-deep D chunk.
// ---------------------------------------------------------------------------
__global__ void __launch_bounds__(256, 4) k_lncc(
    const float* __restrict__ x, const float* __restrict__ y,
    float* __restrict__ partials)
{
    __shared__ float xs[EXT * XS_STR];       // ext slice of x (zero-padded)
    __shared__ float ys[EXT * XS_STR];       // ext slice of y
    __shared__ float wsum[5 * EXT * WS_STR]; // W-filtered, [c][hh 0..23][ww 0..15]
    __shared__ float hsum[5 * TH * WS_STR];  // W+H-filtered, [c][h][w]
    __shared__ float red[256];

    const int t = threadIdx.x;
    const int w0 = blockIdx.x * TW;
    const int h0 = blockIdx.y * TH;
    const int b = blockIdx.z >> 2;       // / NCHUNK
    const int chunk = blockIdx.z & 3;    // % NCHUNK
    const int dc0 = chunk * CHUNK;

    // phase-2 mapping (t < 120): c2 = channel, r2 = ext row
    const int c2 = t / 24, r2 = t % 24;
    // phase-3 mapping (t < 80): c3 = channel, w3 = out col
    const int c3 = t >> 4, w3 = t & 15;
    // phase-4 mapping: output (h4, w4)
    const int h4 = t >> 4, w4 = t & 15;

    // channel row sources for phase 2 (uniform per thread):
    // c: 0 -> x*1, 1 -> y*1, 2 -> x*x, 3 -> y*y, 4 -> x*y
    const float* rowA = (c2 == 1 || c2 == 3) ? &ys[r2 * XS_STR] : &xs[r2 * XS_STR];
    const float* rowB = (c2 == 2) ? &xs[r2 * XS_STR] : &ys[r2 * XS_STR];
    const bool useB = (c2 >= 2);

    // per-thread D-window state (all static indices -> registers)
    float ring[WIN][5];
    float run[5];
#pragma unroll
    for (int i = 0; i < WIN; ++i)
#pragma unroll
        for (int c = 0; c < 5; ++c) ring[i][c] = 0.f;
#pragma unroll
    for (int c = 0; c < 5; ++c) run[c] = 0.f;
    float acc = 0.f;

    const int g0 = dc0 - PAD;
    const int g1 = dc0 + CHUNK + PAD;  // exclusive

    for (int g = g0; g < g1; ++g) {
        float hw5[5];
        if (g >= 0 && g < DD) {   // block-uniform condition: barriers legal
            // ---- P1: stage ext slice of x,y with zero-pad ----
            {
                const long sbase = ((long)(b * DD + g)) * (long)HW;
                for (int e = t; e < EXT * EXT; e += 256) {
                    int r = e / EXT, cl = e - r * EXT;
                    int gh = h0 - PAD + r, gw = w0 - PAD + cl;
                    bool ok = ((unsigned)gh < (unsigned)HH) & ((unsigned)gw < (unsigned)WW);
                    long gi = sbase + (long)gh * WW + gw;
                    float xv = 0.f, yv = 0.f;
                    if (ok) { xv = x[gi]; yv = y[gi]; }
                    xs[r * XS_STR + cl] = xv;
                    ys[r * XS_STR + cl] = yv;
                }
            }
            __syncthreads();
            // ---- P2: sliding W-filter of the 5 quantities (120 threads) ----
            if (t < 120) {
                float q[EXT];
#pragma unroll
                for (int u = 0; u < EXT; ++u) {
                    float a = rowA[u];
                    float bv = useB ? rowB[u] : 1.0f;
                    q[u] = a * bv;
                }
                float s = 0.f;
#pragma unroll
                for (int u = 0; u < WIN; ++u) s += q[u];
                float* wr = &wsum[(c2 * EXT + r2) * WS_STR];
                wr[0] = s;
#pragma unroll
                for (int ww = 1; ww < TW; ++ww) {
                    s += q[ww + 8] - q[ww - 1];
                    wr[ww] = s;
                }
            }
            __syncthreads();
            // ---- P3: sliding H-filter (80 threads) ----
            if (t < 80) {
                const float* wc = &wsum[c3 * EXT * WS_STR + w3];
                float s = 0.f;
#pragma unroll
                for (int v = 0; v < WIN; ++v) s += wc[v * WS_STR];
                float* hc = &hsum[c3 * TH * WS_STR + w3];
                hc[0] = s;
#pragma unroll
                for (int h = 1; h < TH; ++h) {
                    s += wc[(h + 8) * WS_STR] - wc[(h - 1) * WS_STR];
                    hc[h * WS_STR] = s;
                }
            }
            __syncthreads();
#pragma unroll
            for (int c = 0; c < 5; ++c)
                hw5[c] = hsum[(c * TH + h4) * WS_STR + w4];
        } else {
#pragma unroll
            for (int c = 0; c < 5; ++c) hw5[c] = 0.f;
        }
        // ---- P4: D-direction running sum via shift registers ----
#pragma unroll
        for (int c = 0; c < 5; ++c) {
            run[c] += hw5[c] - ring[0][c];
#pragma unroll
            for (int i = 0; i < WIN - 1; ++i) ring[i][c] = ring[i + 1][c];
            ring[WIN - 1][c] = hw5[c];
        }
        int d = g - PAD;
        if (d >= dc0) {  // d < dc1 guaranteed by loop bound
            float sx = run[0], sy = run[1], sxx = run[2], syy = run[3], sxy = run[4];
            float cross = sxy - sx * sy * INV_WS;
            float xv = sxx - sx * sx * INV_WS; xv = fmaxf(xv, EPS);
            float yv = syy - sy * sy * INV_WS; yv = fmaxf(yv, EPS);
            acc += (cross * cross) / (xv * yv);
        }
    }

    // ---- block reduction ----
    red[t] = acc;
    __syncthreads();
    for (int off = 128; off > 0; off >>= 1) {
        if (t < off) red[t] += red[t + off];
        __syncthreads();
    }
    if (t == 0) {
        int bid = (blockIdx.z * HT + blockIdx.y) * WT + blockIdx.x;
        partials[bid] = red[0];
    }
}

// ---------------------------------------------------------------------------
// Final reduce: sum partials in double, write -mean
// ---------------------------------------------------------------------------
__global__ void __launch_bounds__(256) k_finalize(
    const float* __restrict__ partials, float* __restrict__ out)
{
    __shared__ double red[256];
    double s = 0.0;
    for (int i = threadIdx.x; i < NBLK; i += 256) s += (double)partials[i];
    red[threadIdx.x] = s;
    __syncthreads();
    for (int off = 128; off > 0; off >>= 1) {
        if (threadIdx.x < off) red[threadIdx.x] += red[threadIdx.x + off];
        __syncthreads();
    }
    if (threadIdx.x == 0) {
        const double Nvox = (double)BB * DD * HH * WW;
        out[0] = (float)(-red[0] / Nvox);
    }
}

extern "C" void kernel_launch(void* const* d_in, const int* in_sizes, int n_in,
                              void* d_out, int out_size, void* d_ws, size_t ws_size,
                              hipStream_t stream) {
    (void)in_sizes; (void)n_in; (void)out_size; (void)ws_size;
    const float* x = (const float*)d_in[0];
    const float* y = (const float*)d_in[1];
    float* out = (float*)d_out;
    float* partials = (float*)d_ws;

    dim3 grid(WT, HT, BB * NCHUNK);
    k_lncc<<<grid, 256, 0, stream>>>(x, y, partials);
    k_finalize<<<1, 256, 0, stream>>>(partials, out);
}